// Round 2
// baseline (10174.143 us; speedup 1.0000x reference)
//
#include <hip/hip_runtime.h>
#include <hip/hip_bf16.h>

typedef unsigned short ushortT;
typedef __attribute__((ext_vector_type(8))) short bf16x8;
typedef __attribute__((ext_vector_type(4))) float f32x4;

#define B_SZ 64
#define T_SZ 512
#define D_SZ 256
#define U_SZ 512
#define M_SZ 64

// ---------- helpers ----------
__device__ __forceinline__ float b2f(ushortT u) {
    unsigned v = ((unsigned)u) << 16;
    union { unsigned u; float f; } c; c.u = v; return c.f;
}
__device__ __forceinline__ ushortT f2b(float f) {
    __hip_bfloat16 h = __float2bfloat16(f);
    union { __hip_bfloat16 h; ushortT u; } c; c.h = h; return c.u;
}
__device__ __forceinline__ float clip10(float v) {
    return fminf(fmaxf(v, -10.f), 10.f);
}
__device__ __forceinline__ float tanh_fast(float z) {
    float e = __expf(2.f * z);
    return 1.f - 2.f / (e + 1.f);   // inf-safe: e=inf -> 1, e=0 -> -1
}
__device__ __forceinline__ float sigm_fast(float z) {
    return 1.f / (1.f + __expf(-z));
}

// ---------- prep: x -> clipped bf16 ----------
__global__ void prep_xb_k(const float* __restrict__ x, ushortT* __restrict__ xb) {
    const int n4 = (B_SZ * T_SZ * D_SZ) / 4;
    for (int i = blockIdx.x * blockDim.x + threadIdx.x; i < n4; i += gridDim.x * blockDim.x) {
        float4 v = ((const float4*)x)[i];
        ushort4 o;
        o.x = f2b(clip10(v.x));
        o.y = f2b(clip10(v.y));
        o.z = f2b(clip10(v.z));
        o.w = f2b(clip10(v.w));
        ((ushort4*)xb)[i] = o;
    }
}

// ---------- prep: U^T and W^T bf16, col-major-transposed ----------
// col c: c<2048 -> gate g=c>>9, unit u=c&511 ; c>=2048 -> Ue/We col c-2048
__global__ void prep_uw_k(const float* __restrict__ Ui, const float* __restrict__ Uf,
                          const float* __restrict__ Uo, const float* __restrict__ Uc,
                          const float* __restrict__ Ue,
                          const float* __restrict__ Wi, const float* __restrict__ Wf,
                          const float* __restrict__ Wo, const float* __restrict__ Wc,
                          const float* __restrict__ We,
                          ushortT* __restrict__ UslT, ushortT* __restrict__ WslT) {
    const int NU = 2112 * 512;
    const int NW = 2112 * 256;
    for (int i = blockIdx.x * blockDim.x + threadIdx.x; i < NU + NW; i += gridDim.x * blockDim.x) {
        if (i < NU) {
            int c = i >> 9, k = i & 511;
            float v;
            if (c < 2048) {
                int g = c >> 9, u = c & 511;
                const float* U = (g == 0) ? Ui : (g == 1) ? Uf : (g == 2) ? Uo : Uc;
                v = U[k * 512 + u];
            } else {
                v = Ue[k * 64 + (c - 2048)];
            }
            UslT[i] = f2b(v);
        } else {
            int j = i - NU;
            int c = j >> 8, k = j & 255;
            float v;
            if (c < 2048) {
                int g = c >> 9, u = c & 511;
                const float* W = (g == 0) ? Wi : (g == 1) ? Wf : (g == 2) ? Wo : Wc;
                v = W[k * 512 + u];
            } else {
                v = We[k * 64 + (c - 2048)];
            }
            WslT[j] = f2b(v);
        }
    }
}

// ---------- persistent recurrent kernel ----------
// 256 WGs x 256 threads, plain launch: grid == 256 == #CUs, 58KB LDS + 4 waves
// guarantees >=1 block/CU occupancy, so ALL blocks are co-resident at dispatch.
// Groups (bid&7) are fully independent; only the 32 WGs of one group sync.
__global__ __launch_bounds__(256, 1) void xlstm_rec(
    const ushortT* __restrict__ xb,    // [B*T][256] bf16 (clipped)
    const ushortT* __restrict__ UslT,  // [2112][512] bf16
    const ushortT* __restrict__ WslT,  // [2112][256] bf16
    const float* __restrict__ Wm,      // [256][512] fp32
    const float* __restrict__ bi_p, const float* __restrict__ bf_p,
    const float* __restrict__ bo_p, const float* __restrict__ bc_p,
    const float* __restrict__ be_p,
    ushortT* __restrict__ Hbuf,        // [2][64][512] bf16
    unsigned* __restrict__ flags,      // [256], flags[grp*32+rank]
    float* __restrict__ out)           // [64][512][512] fp32
{
    const int bid = blockIdx.x, tid = threadIdx.x;
    const int grp = bid & 7, rank = bid >> 3;
    const int wave = tid >> 6, lane = tid & 63;
    const int b0 = grp << 3;     // batch base
    const int u0 = rank << 4;    // unit base

    // LDS. memF idx(pb,s,pu) = pb*1032 + s*16 + pu  (stride 1032 -> bank skew 8 per pb)
    __shared__ float memF[8 * 1032 + 24];
    __shared__ float g_lds[4][8][16];   // i,f,o,ctilde activations
    __shared__ float e_lds[8][68];      // softmax workspace (padded)
    __shared__ float wmL[256][16];      // Wm slice
    __shared__ ushortT xbL[8][272];     // x rows staged (padded; row base 544B = 16B-aligned)

    for (int i = tid; i < 8 * 1032 + 24; i += 256) memF[i] = 0.f;
    for (int i = tid; i < 256 * 16; i += 256) {
        int k = i >> 4, u = i & 15;
        wmL[k][u] = Wm[k * 512 + u0 + u];
    }

    // ---- load register-resident B fragments (weights) ----
    // wave's col j = wave*32 + nt*16 + (lane&15); j<64: gate cols, j>=64: e col j-64
    int cols[2];
    float biasv[2];
#pragma unroll
    for (int nt = 0; nt < 2; ++nt) {
        int j = wave * 32 + nt * 16 + (lane & 15);
        if (j < 64) {
            int g = j >> 4, u = u0 + (j & 15);
            cols[nt] = g * 512 + u;
            biasv[nt] = (g == 0) ? bi_p[u] : (g == 1) ? bf_p[u] : (g == 2) ? bo_p[u] : bc_p[u];
        } else {
            cols[nt] = 2048 + (j - 64);
            biasv[nt] = be_p[j - 64];
        }
    }
    const int koct = (lane >> 4) * 8;
    bf16x8 B1[2][8], B2[2][16];
#pragma unroll
    for (int nt = 0; nt < 2; ++nt) {
        const ushortT* bw = WslT + cols[nt] * 256;
#pragma unroll
        for (int kt = 0; kt < 8; ++kt)
            B1[nt][kt] = *(const bf16x8*)(bw + kt * 32 + koct);
        const ushortT* bu = UslT + cols[nt] * 512;
#pragma unroll
        for (int kt = 0; kt < 16; ++kt)
            B2[nt][kt] = *(const bf16x8*)(bu + kt * 32 + koct);
    }

    const int arow = lane & 7;                 // A-operand batch row (rows 8-15 duplicate 0-7)
    const bool is_pw = (tid >= 64 && tid < 192);
    const int pb = (tid - 64) >> 4;            // pointwise batch
    const int pu = (tid - 64) & 15;            // pointwise unit

    __syncthreads();

    float zm = 0.f;

    for (int t = 0; t < T_SZ; ++t) {
        const int wp = t & 1, rp = wp ^ 1;

        // stage x rows for this t (full 256 ushorts/row: 16 threads x 32B each)
        if (tid < 128) {
            int b = tid >> 4, ch = tid & 15;
            const int4* src = (const int4*)(xb + ((b0 + b) * T_SZ + t) * D_SZ + ch * 16);
            int4* dst = (int4*)(&xbL[b][ch * 16]);
            dst[0] = src[0];
            dst[1] = src[1];
        }
        // prefetch x MFMA A-fragments (independent of h)
        bf16x8 a1f[8];
        {
            const ushortT* xrow = xb + ((b0 + arow) * T_SZ + t) * D_SZ + koct;
#pragma unroll
            for (int kt = 0; kt < 8; ++kt)
                a1f[kt] = *(const bf16x8*)(xrow + kt * 32);
        }
        __syncthreads();   // xbL ready

        // wave0: inter-WG barrier poll; waves1,2: compute zm = x_t @ Wm (off critical path)
        if (wave == 0) {
            if (t > 0) {
                const unsigned tgt = (unsigned)t;
                unsigned* fp = flags + grp * 32 + (lane & 31);
                while (true) {
                    unsigned v = (lane < 32)
                        ? __hip_atomic_load(fp, __ATOMIC_ACQUIRE, __HIP_MEMORY_SCOPE_AGENT)
                        : 0xFFFFFFFFu;
                    if (__all((lane >= 32) || (v >= tgt))) break;
                    __builtin_amdgcn_s_sleep(1);
                }
                __threadfence();
            }
        } else if (is_pw) {
            float acc = 0.f;
#pragma unroll 8
            for (int k = 0; k < 256; k += 2) {
                unsigned pr = *(const unsigned*)&xbL[pb][k];
                acc = fmaf(b2f((ushortT)(pr & 0xFFFFu)), wmL[k][pu], acc);
                acc = fmaf(b2f((ushortT)(pr >> 16)), wmL[k + 1][pu], acc);
            }
            zm = acc;
        }
        __syncthreads();   // barrier complete: H[rp] = h_{t-1} visible

        // ---- MFMA: z = x_t@W + h_{t-1}@U  (fp32 accum) ----
        f32x4 acc0 = {0.f, 0.f, 0.f, 0.f}, acc1 = {0.f, 0.f, 0.f, 0.f};
#pragma unroll
        for (int kt = 0; kt < 8; ++kt) {
            acc0 = __builtin_amdgcn_mfma_f32_16x16x32_bf16(a1f[kt], B1[0][kt], acc0, 0, 0, 0);
            acc1 = __builtin_amdgcn_mfma_f32_16x16x32_bf16(a1f[kt], B1[1][kt], acc1, 0, 0, 0);
        }
        {
            const ushortT* hrow = Hbuf + (rp << 15) + (b0 + arow) * 512 + koct;
#pragma unroll
            for (int kt = 0; kt < 16; ++kt) {
                bf16x8 a = *(const bf16x8*)(hrow + kt * 32);
                acc0 = __builtin_amdgcn_mfma_f32_16x16x32_bf16(a, B2[0][kt], acc0, 0, 0, 0);
                acc1 = __builtin_amdgcn_mfma_f32_16x16x32_bf16(a, B2[1][kt], acc1, 0, 0, 0);
            }
        }

        // ---- epilogue: bias + clip + activation -> LDS ----
        // C/D layout: col=lane&15, row=(lane>>4)*4+i ; rows 0..7 live in lanes 0..31
        if (lane < 32) {
#pragma unroll
            for (int nt = 0; nt < 2; ++nt) {
                int j = wave * 32 + nt * 16 + (lane & 15);
                f32x4 a = nt ? acc1 : acc0;
#pragma unroll
                for (int i = 0; i < 4; ++i) {
                    int b = ((lane >> 4) << 2) + i;   // 0..7
                    float z = clip10(a[i] + biasv[nt]);
                    if (j < 64) {
                        int g = j >> 4;
                        g_lds[g][b][j & 15] = (g == 3) ? tanh_fast(z) : sigm_fast(z);
                    } else {
                        e_lds[b][j - 64] = z;
                    }
                }
            }
        }
        __syncthreads();

        // ---- softmax over 64 mem slots (wave 0; 8 lanes per batch) ----
        if (wave == 0) {
            int b = lane >> 3, c8 = (lane & 7) * 8;
            float v[8], m = -1e30f;
#pragma unroll
            for (int q = 0; q < 8; ++q) { v[q] = e_lds[b][c8 + q]; m = fmaxf(m, v[q]); }
#pragma unroll
            for (int d = 1; d < 8; d <<= 1) m = fmaxf(m, __shfl_xor(m, d));
            float s = 0.f;
#pragma unroll
            for (int q = 0; q < 8; ++q) { v[q] = __expf(v[q] - m); s += v[q]; }
#pragma unroll
            for (int d = 1; d < 8; d <<= 1) s += __shfl_xor(s, d);
            float inv = 1.f / s;
#pragma unroll
            for (int q = 0; q < 8; ++q) e_lds[b][c8 + q] = v[q] * inv;
        }
        __syncthreads();

        // ---- pointwise: attention, c, h, ring-buffer update ----
        if (is_pw) {
            float attn = 0.f;
            const float* mrow = memF + pb * 1032 + pu;
#pragma unroll 16
            for (int s = 0; s < 64; ++s) {
                attn = fmaf(mrow[s * 16], e_lds[pb][((unsigned)(t - 1 - s)) & 63], attn);
            }
            float ig = g_lds[0][pb][pu];
            float fg = g_lds[1][pb][pu];
            float og = g_lds[2][pb][pu];
            float ct = g_lds[3][pb][pu];
            float c = fg * (attn + zm) + ig * ct;
            float h = og * tanh_fast(c);
            memF[pb * 1032 + (t & 63) * 16 + pu] = c;
            Hbuf[(wp << 15) + (b0 + pb) * 512 + u0 + pu] = f2b(h);
            out[((b0 + pb) * T_SZ + t) * U_SZ + u0 + pu] = h;
        }
        __syncthreads();   // all WG stores executed (vmcnt drained) before release

        // release: this WG finished step t
        if (tid == 0) {
            __threadfence();   // flush to device scope (covers whole WG's stores)
            __hip_atomic_store(flags + grp * 32 + rank, (unsigned)(t + 1),
                               __ATOMIC_RELEASE, __HIP_MEMORY_SCOPE_AGENT);
        }
    }
}

// ---------- launch ----------
extern "C" void kernel_launch(void* const* d_in, const int* in_sizes, int n_in,
                              void* d_out, int out_size, void* d_ws, size_t ws_size,
                              hipStream_t stream) {
    const float* x  = (const float*)d_in[0];
    const float* Wi = (const float*)d_in[1];
    const float* Ui = (const float*)d_in[2];
    const float* bi = (const float*)d_in[3];
    const float* Wf = (const float*)d_in[4];
    const float* Uf = (const float*)d_in[5];
    const float* bf = (const float*)d_in[6];
    const float* Wo = (const float*)d_in[7];
    const float* Uo = (const float*)d_in[8];
    const float* bo = (const float*)d_in[9];
    const float* Wc = (const float*)d_in[10];
    const float* Uc = (const float*)d_in[11];
    const float* bc = (const float*)d_in[12];
    const float* Wm = (const float*)d_in[13];
    const float* We = (const float*)d_in[14];
    const float* Ue = (const float*)d_in[15];
    const float* be = (const float*)d_in[16];

    char* ws = (char*)d_ws;
    const size_t off_xb    = 0;
    const size_t off_uslt  = off_xb + (size_t)B_SZ * T_SZ * D_SZ * 2;       // 16,777,216
    const size_t off_wslt  = off_uslt + (size_t)2112 * 512 * 2;             // +2,162,688
    const size_t off_hbuf  = off_wslt + (size_t)2112 * 256 * 2;             // +1,081,344
    const size_t off_flags = off_hbuf + (size_t)2 * 64 * 512 * 2;           // +131,072
    ushortT* xb      = (ushortT*)(ws + off_xb);
    ushortT* UslT    = (ushortT*)(ws + off_uslt);
    ushortT* WslT    = (ushortT*)(ws + off_wslt);
    ushortT* Hb      = (ushortT*)(ws + off_hbuf);
    unsigned* flags  = (unsigned*)(ws + off_flags);
    float* out = (float*)d_out;

    // zero H double-buffer + flags (contiguous)
    hipMemsetAsync(ws + off_hbuf, 0, 131072 + 1024, stream);

    prep_xb_k<<<2048, 256, 0, stream>>>(x, xb);
    prep_uw_k<<<2048, 256, 0, stream>>>(Ui, Uf, Uo, Uc, Ue, Wi, Wf, Wo, Wc, We, UslT, WslT);

    xlstm_rec<<<dim3(256), dim3(256), 0, stream>>>(
        xb, UslT, WslT, Wm, bi, bf, bo, bc, be, Hb, flags, out);
}

// Round 3
// 5059.267 us; speedup vs baseline: 2.0110x; 2.0110x over previous
//
#include <hip/hip_runtime.h>
#include <hip/hip_bf16.h>

typedef unsigned short ushortT;
typedef __attribute__((ext_vector_type(8))) short bf16x8;
typedef __attribute__((ext_vector_type(4))) float f32x4;
typedef __attribute__((ext_vector_type(4))) int i32x4;

#define B_SZ 64
#define T_SZ 512
#define D_SZ 256
#define U_SZ 512
#define M_SZ 64

// ---------- helpers ----------
__device__ __forceinline__ float b2f(ushortT u) {
    unsigned v = ((unsigned)u) << 16;
    union { unsigned u; float f; } c; c.u = v; return c.f;
}
__device__ __forceinline__ ushortT f2b(float f) {
    __hip_bfloat16 h = __float2bfloat16(f);
    union { __hip_bfloat16 h; ushortT u; } c; c.h = h; return c.u;
}
__device__ __forceinline__ float clip10(float v) {
    return fminf(fmaxf(v, -10.f), 10.f);
}
__device__ __forceinline__ float tanh_fast(float z) {
    float e = __expf(2.f * z);
    return 1.f - 2.f / (e + 1.f);   // inf-safe
}
__device__ __forceinline__ float sigm_fast(float z) {
    return 1.f / (1.f + __expf(-z));
}

// ---------- prep: x -> clipped bf16 ----------
__global__ void prep_xb_k(const float* __restrict__ x, ushortT* __restrict__ xb) {
    const int n4 = (B_SZ * T_SZ * D_SZ) / 4;
    for (int i = blockIdx.x * blockDim.x + threadIdx.x; i < n4; i += gridDim.x * blockDim.x) {
        float4 v = ((const float4*)x)[i];
        ushort4 o;
        o.x = f2b(clip10(v.x));
        o.y = f2b(clip10(v.y));
        o.z = f2b(clip10(v.z));
        o.w = f2b(clip10(v.w));
        ((ushort4*)xb)[i] = o;
    }
}

// ---------- prep: U^T and W^T bf16, col-major-transposed ----------
__global__ void prep_uw_k(const float* __restrict__ Ui, const float* __restrict__ Uf,
                          const float* __restrict__ Uo, const float* __restrict__ Uc,
                          const float* __restrict__ Ue,
                          const float* __restrict__ Wi, const float* __restrict__ Wf,
                          const float* __restrict__ Wo, const float* __restrict__ Wc,
                          const float* __restrict__ We,
                          ushortT* __restrict__ UslT, ushortT* __restrict__ WslT) {
    const int NU = 2112 * 512;
    const int NW = 2112 * 256;
    for (int i = blockIdx.x * blockDim.x + threadIdx.x; i < NU + NW; i += gridDim.x * blockDim.x) {
        if (i < NU) {
            int c = i >> 9, k = i & 511;
            float v;
            if (c < 2048) {
                int g = c >> 9, u = c & 511;
                const float* U = (g == 0) ? Ui : (g == 1) ? Uf : (g == 2) ? Uo : Uc;
                v = U[k * 512 + u];
            } else {
                v = Ue[k * 64 + (c - 2048)];
            }
            UslT[i] = f2b(v);
        } else {
            int j = i - NU;
            int c = j >> 8, k = j & 255;
            float v;
            if (c < 2048) {
                int g = c >> 9, u = c & 511;
                const float* W = (g == 0) ? Wi : (g == 1) ? Wf : (g == 2) ? Wo : Wc;
                v = W[k * 512 + u];
            } else {
                v = We[k * 64 + (c - 2048)];
            }
            WslT[j] = f2b(v);
        }
    }
}

// ---------- persistent recurrent kernel ----------
// 256 WGs x 256 threads, 1 block/CU (grid == #CUs) -> all co-resident.
// Group = bid&7 (8 batches); rank = bid>>3 (16 units). Shared state (h, flags)
// moves through LLC via sc0 sc1 accesses -> no L2 invalidates/writebacks needed.
__global__ __launch_bounds__(256, 1) void xlstm_rec(
    const ushortT* __restrict__ xb,    // [B*T][256] bf16 (clipped)
    const ushortT* __restrict__ UslT,  // [2112][512] bf16
    const ushortT* __restrict__ WslT,  // [2112][256] bf16
    const float* __restrict__ Wm,      // [256][512] fp32
    const float* __restrict__ bi_p, const float* __restrict__ bf_p,
    const float* __restrict__ bo_p, const float* __restrict__ bc_p,
    const float* __restrict__ be_p,
    ushortT* __restrict__ Hbuf,        // [2][64][512] bf16
    unsigned* __restrict__ flags,      // [256], flags[grp*32+rank]
    float* __restrict__ out)           // [64][512][512] fp32
{
    const int bid = blockIdx.x, tid = threadIdx.x;
    const int grp = bid & 7, rank = bid >> 3;
    const int wave = tid >> 6, lane = tid & 63;
    const int b0 = grp << 3;     // batch base
    const int u0 = rank << 4;    // unit base

    __shared__ float memF[8 * 1032 + 24];   // ring buffer of c, idx = pb*1032 + slot*16 + pu
    __shared__ float g_lds[4][8][16];       // i,f,o,ctilde activations
    __shared__ float e_lds[8][68];          // raw clipped e-logits
    __shared__ float wmL[256][16];          // Wm slice
    __shared__ ushortT xbL[2][8][272];      // x rows staged, double-buffered

    for (int i = tid; i < 8 * 1032 + 24; i += 256) memF[i] = 0.f;
    for (int i = tid; i < 256 * 16; i += 256) {
        int k = i >> 4, u = i & 15;
        wmL[k][u] = Wm[k * 512 + u0 + u];
    }

    // ---- register-resident weight B-fragments ----
    int cols[2];
    float biasv[2];
#pragma unroll
    for (int nt = 0; nt < 2; ++nt) {
        int j = wave * 32 + nt * 16 + (lane & 15);
        if (j < 64) {
            int g = j >> 4, u = u0 + (j & 15);
            cols[nt] = g * 512 + u;
            biasv[nt] = (g == 0) ? bi_p[u] : (g == 1) ? bf_p[u] : (g == 2) ? bo_p[u] : bc_p[u];
        } else {
            cols[nt] = 2048 + (j - 64);
            biasv[nt] = be_p[j - 64];
        }
    }
    const int koct = (lane >> 4) * 8;
    bf16x8 B1[2][8], B2[2][16];
#pragma unroll
    for (int nt = 0; nt < 2; ++nt) {
        const ushortT* bw = WslT + cols[nt] * 256;
#pragma unroll
        for (int kt = 0; kt < 8; ++kt)
            B1[nt][kt] = *(const bf16x8*)(bw + kt * 32 + koct);
        const ushortT* bu = UslT + cols[nt] * 512;
#pragma unroll
        for (int kt = 0; kt < 16; ++kt)
            B2[nt][kt] = *(const bf16x8*)(bu + kt * 32 + koct);
    }

    const int arow = lane & 7;                 // A-operand batch row
    const bool is_pw = (tid >= 64 && tid < 192);
    const int pb = (tid - 64) >> 3 >> 1;       // == (tid-64)>>4, pointwise batch
    const int pu = (tid - 64) & 15;            // pointwise unit

    // stage x for t=0
    if (tid < 128) {
        int b = tid >> 4, ch = tid & 15;
        const int4* src = (const int4*)(xb + ((b0 + b) * T_SZ + 0) * D_SZ + ch * 16);
        int4* dst = (int4*)(&xbL[0][b][ch * 16]);
        dst[0] = src[0];
        dst[1] = src[1];
    }
    __syncthreads();

    float zm = 0.f;

    for (int t = 0; t < T_SZ; ++t) {
        const int wp = t & 1, rp = wp ^ 1, cur = t & 1, nxt = cur ^ 1;

        // ---- phase A: a1f prefetch (all); wave0 polls; pw threads compute zm ----
        bf16x8 a1f[8];
        {
            const ushortT* xrow = xb + ((b0 + arow) * T_SZ + t) * D_SZ + koct;
#pragma unroll
            for (int kt = 0; kt < 8; ++kt)
                a1f[kt] = *(const bf16x8*)(xrow + kt * 32);
        }
        if (wave == 0) {
            if (t > 0) {
                const unsigned tgt = (unsigned)t;
                const unsigned* fp = flags + grp * 32 + (lane & 31);
                while (true) {
                    unsigned vv;
                    // relaxed LLC-coherent load + wait folded into one asm block
                    asm volatile("global_load_dword %0, %1, off sc0 sc1\n\t"
                                 "s_waitcnt vmcnt(0)"
                                 : "=v"(vv) : "v"(fp) : "memory");
                    if (__all((lane >= 32) || (vv >= tgt))) break;
                    __builtin_amdgcn_s_sleep(1);
                }
            }
        } else if (is_pw) {
            float acc = 0.f;
#pragma unroll 8
            for (int k = 0; k < 256; k += 2) {
                unsigned pr = *(const unsigned*)&xbL[cur][pb][k];
                acc = fmaf(b2f((ushortT)(pr & 0xFFFFu)), wmL[k][pu], acc);
                acc = fmaf(b2f((ushortT)(pr >> 16)), wmL[k + 1][pu], acc);
            }
            zm = acc;
        }
        __syncthreads();   // barrier: h_{t-1} released by all WGs; zm ready

        // ---- phase B: MFMA z = x@W + h@U, epilogue to LDS ----
        // issue h loads through LLC (sc0 sc1: bypass potentially-stale L2)
        i32x4 hfrag[16];
        {
            const ushortT* hrow = Hbuf + (rp << 15) + (b0 + arow) * 512 + koct;
#pragma unroll
            for (int kt = 0; kt < 16; ++kt) {
                asm volatile("global_load_dwordx4 %0, %1, off sc0 sc1"
                             : "=v"(hfrag[kt]) : "v"(hrow + kt * 32) : "memory");
            }
        }
        f32x4 acc0 = {0.f, 0.f, 0.f, 0.f}, acc1 = {0.f, 0.f, 0.f, 0.f};
#pragma unroll
        for (int kt = 0; kt < 8; ++kt) {
            acc0 = __builtin_amdgcn_mfma_f32_16x16x32_bf16(a1f[kt], B1[0][kt], acc0, 0, 0, 0);
            acc1 = __builtin_amdgcn_mfma_f32_16x16x32_bf16(a1f[kt], B1[1][kt], acc1, 0, 0, 0);
        }
        asm volatile("s_waitcnt vmcnt(0)" ::: "memory");
        __builtin_amdgcn_sched_barrier(0);   // rule #18: keep MFMAs below the wait
#pragma unroll
        for (int kt = 0; kt < 16; ++kt) {
            bf16x8 a = __builtin_bit_cast(bf16x8, hfrag[kt]);
            acc0 = __builtin_amdgcn_mfma_f32_16x16x32_bf16(a, B2[0][kt], acc0, 0, 0, 0);
            acc1 = __builtin_amdgcn_mfma_f32_16x16x32_bf16(a, B2[1][kt], acc1, 0, 0, 0);
        }
        // epilogue: C/D layout col=lane&15, row=(lane>>4)*4+i; rows 0..7 in lanes 0..31
        if (lane < 32) {
#pragma unroll
            for (int nt = 0; nt < 2; ++nt) {
                int j = wave * 32 + nt * 16 + (lane & 15);
                f32x4 a = nt ? acc1 : acc0;
#pragma unroll
                for (int i = 0; i < 4; ++i) {
                    int b = ((lane >> 4) << 2) + i;   // 0..7
                    float z = clip10(a[i] + biasv[nt]);
                    if (j < 64) {
                        int g = j >> 4;
                        g_lds[g][b][j & 15] = (g == 3) ? tanh_fast(z) : sigm_fast(z);
                    } else {
                        e_lds[b][j - 64] = z;        // raw logit
                    }
                }
            }
        }
        __syncthreads();

        // ---- phase C: pointwise (softmax fused) ; waves 0,3 stage x for t+1 ----
        if (is_pw) {
            // softmax max (redundant per pu - no extra barrier needed)
            float m = -1e30f;
#pragma unroll
            for (int q = 0; q < 16; ++q) {
                float4 v = *(const float4*)&e_lds[pb][q * 4];
                m = fmaxf(m, fmaxf(fmaxf(v.x, v.y), fmaxf(v.z, v.w)));
            }
            float s = 0.f, attn = 0.f;
            const float* mrow = memF + pb * 1032 + pu;
#pragma unroll 8
            for (int p = 0; p < 64; ++p) {
                float w = __expf(e_lds[pb][(unsigned)(t - 1 - p) & 63] - m);
                s += w;
                attn = fmaf(w, mrow[p * 16], attn);
            }
            attn /= s;
            float ig = g_lds[0][pb][pu];
            float fg = g_lds[1][pb][pu];
            float og = g_lds[2][pb][pu];
            float ct = g_lds[3][pb][pu];
            float c = fg * (attn + zm) + ig * ct;
            float h = og * tanh_fast(c);
            memF[pb * 1032 + (t & 63) * 16 + pu] = c;
            out[((b0 + pb) * T_SZ + t) * U_SZ + u0 + pu] = h;
            // h -> LLC (write-through, device-coherent)
            ushortT hv = f2b(h);
            const ushortT* haddr = Hbuf + (wp << 15) + (b0 + pb) * 512 + u0 + pu;
            asm volatile("global_store_short %0, %1, off sc0 sc1"
                         :: "v"(haddr), "v"((unsigned)hv) : "memory");
            // drain this wave's stores so the post-barrier flag release implies
            // h is at the LLC (vmcnt acks sc1 stores at device coherence point)
            asm volatile("s_waitcnt vmcnt(0)" ::: "memory");
        } else if (t + 1 < T_SZ) {
            // waves 0 and 3: stage x rows for t+1
            int st = (tid < 64) ? tid : (tid - 128);   // 0..127
            int b = st >> 4, ch = st & 15;
            const int4* src = (const int4*)(xb + ((b0 + b) * T_SZ + (t + 1)) * D_SZ + ch * 16);
            int4* dst = (int4*)(&xbL[nxt][b][ch * 16]);
            dst[0] = src[0];
            dst[1] = src[1];
        }
        __syncthreads();   // all h stores ack'd (per-wave vmcnt(0) above) before release

        // release: flag stores strictly after this WG's h is LLC-visible
        if (tid == 0) {
            __hip_atomic_store(flags + grp * 32 + rank, (unsigned)(t + 1),
                               __ATOMIC_RELAXED, __HIP_MEMORY_SCOPE_AGENT);
        }
    }
}

// ---------- launch ----------
extern "C" void kernel_launch(void* const* d_in, const int* in_sizes, int n_in,
                              void* d_out, int out_size, void* d_ws, size_t ws_size,
                              hipStream_t stream) {
    const float* x  = (const float*)d_in[0];
    const float* Wi = (const float*)d_in[1];
    const float* Ui = (const float*)d_in[2];
    const float* bi = (const float*)d_in[3];
    const float* Wf = (const float*)d_in[4];
    const float* Uf = (const float*)d_in[5];
    const float* bf = (const float*)d_in[6];
    const float* Wo = (const float*)d_in[7];
    const float* Uo = (const float*)d_in[8];
    const float* bo = (const float*)d_in[9];
    const float* Wc = (const float*)d_in[10];
    const float* Uc = (const float*)d_in[11];
    const float* bc = (const float*)d_in[12];
    const float* Wm = (const float*)d_in[13];
    const float* We = (const float*)d_in[14];
    const float* Ue = (const float*)d_in[15];
    const float* be = (const float*)d_in[16];

    char* ws = (char*)d_ws;
    const size_t off_xb    = 0;
    const size_t off_uslt  = off_xb + (size_t)B_SZ * T_SZ * D_SZ * 2;       // 16,777,216
    const size_t off_wslt  = off_uslt + (size_t)2112 * 512 * 2;             // +2,162,688
    const size_t off_hbuf  = off_wslt + (size_t)2112 * 256 * 2;             // +1,081,344
    const size_t off_flags = off_hbuf + (size_t)2 * 64 * 512 * 2;           // +131,072
    ushortT* xb      = (ushortT*)(ws + off_xb);
    ushortT* UslT    = (ushortT*)(ws + off_uslt);
    ushortT* WslT    = (ushortT*)(ws + off_wslt);
    ushortT* Hb      = (ushortT*)(ws + off_hbuf);
    unsigned* flags  = (unsigned*)(ws + off_flags);
    float* out = (float*)d_out;

    // zero H double-buffer + flags (contiguous)
    hipMemsetAsync(ws + off_hbuf, 0, 131072 + 1024, stream);

    prep_xb_k<<<2048, 256, 0, stream>>>(x, xb);
    prep_uw_k<<<2048, 256, 0, stream>>>(Ui, Uf, Uo, Uc, Ue, Wi, Wf, Wo, Wc, We, UslT, WslT);

    xlstm_rec<<<dim3(256), dim3(256), 0, stream>>>(
        xb, UslT, WslT, Wm, bi, bf, bo, bc, be, Hb, flags, out);
}

// Round 5
// 2760.906 us; speedup vs baseline: 3.6851x; 1.8325x over previous
//
#include <hip/hip_runtime.h>
#include <hip/hip_bf16.h>

typedef unsigned short ushortT;
typedef __attribute__((ext_vector_type(8))) short bf16x8;
typedef __attribute__((ext_vector_type(4))) float f32x4;
typedef __attribute__((ext_vector_type(4))) int i32x4;

#define B_SZ 64
#define T_SZ 512
#define D_SZ 256
#define U_SZ 512
#define M_SZ 64

// ---------- helpers ----------
__device__ __forceinline__ float b2f(ushortT u) {
    unsigned v = ((unsigned)u) << 16;
    union { unsigned u; float f; } c; c.u = v; return c.f;
}
__device__ __forceinline__ ushortT f2b(float f) {
    __hip_bfloat16 h = __float2bfloat16(f);
    union { __hip_bfloat16 h; ushortT u; } c; c.h = h; return c.u;
}
__device__ __forceinline__ float clip10(float v) {
    return fminf(fmaxf(v, -10.f), 10.f);
}
__device__ __forceinline__ float tanh_fast(float z) {
    float e = __expf(2.f * z);
    return 1.f - 2.f / (e + 1.f);   // inf-safe
}
__device__ __forceinline__ float sigm_fast(float z) {
    return 1.f / (1.f + __expf(-z));
}

// ---------- prep: x -> clipped bf16 ----------
__global__ void prep_xb_k(const float* __restrict__ x, ushortT* __restrict__ xb) {
    const int n4 = (B_SZ * T_SZ * D_SZ) / 4;
    for (int i = blockIdx.x * blockDim.x + threadIdx.x; i < n4; i += gridDim.x * blockDim.x) {
        float4 v = ((const float4*)x)[i];
        ushort4 o;
        o.x = f2b(clip10(v.x));
        o.y = f2b(clip10(v.y));
        o.z = f2b(clip10(v.z));
        o.w = f2b(clip10(v.w));
        ((ushort4*)xb)[i] = o;
    }
}

// ---------- prep: U^T and W^T bf16 (transposed, col-major rows) ----------
// UslT cols: 0..2047 gate U cols, 2048..2111 Ue cols.
// WslT cols: 0..2047 gate W cols, 2048..2111 We cols, 2112..2623 Wm cols.
__global__ void prep_uw_k(const float* __restrict__ Ui, const float* __restrict__ Uf,
                          const float* __restrict__ Uo, const float* __restrict__ Uc,
                          const float* __restrict__ Ue,
                          const float* __restrict__ Wi, const float* __restrict__ Wf,
                          const float* __restrict__ Wo, const float* __restrict__ Wc,
                          const float* __restrict__ We, const float* __restrict__ Wm,
                          ushortT* __restrict__ UslT, ushortT* __restrict__ WslT) {
    const int NU = 2112 * 512;
    const int NW = 2624 * 256;
    for (int i = blockIdx.x * blockDim.x + threadIdx.x; i < NU + NW; i += gridDim.x * blockDim.x) {
        if (i < NU) {
            int c = i >> 9, k = i & 511;
            float v;
            if (c < 2048) {
                int g = c >> 9, u = c & 511;
                const float* U = (g == 0) ? Ui : (g == 1) ? Uf : (g == 2) ? Uo : Uc;
                v = U[k * 512 + u];
            } else {
                v = Ue[k * 64 + (c - 2048)];
            }
            UslT[i] = f2b(v);
        } else {
            int j = i - NU;
            int c = j >> 8, k = j & 255;
            float v;
            if (c < 2048) {
                int g = c >> 9, u = c & 511;
                const float* W = (g == 0) ? Wi : (g == 1) ? Wf : (g == 2) ? Wo : Wc;
                v = W[k * 512 + u];
            } else if (c < 2112) {
                v = We[k * 64 + (c - 2048)];
            } else {
                v = Wm[k * 512 + (c - 2112)];
            }
            WslT[j] = f2b(v);
        }
    }
}

// ---------- flag helpers: ALWAYS LLC-coherent (sc0 sc1) — placement-safe ----------
__device__ __forceinline__ unsigned flag_ld(const unsigned* p) {
    unsigned v;
    asm volatile("global_load_dword %0, %1, off sc0 sc1\n\ts_waitcnt vmcnt(0)"
                 : "=v"(v) : "v"(p) : "memory");
    return v;
}
__device__ __forceinline__ void flag_st(const unsigned* p, unsigned v) {
    asm volatile("global_store_dword %0, %1, off sc0 sc1" :: "v"(p), "v"(v) : "memory");
}

#define MEMF_PB 1096   // floats per batch block (16 rows x 68 + 8 skew)
#define MEMF_ROW 68

// ---------- persistent recurrent kernel ----------
// 256 WGs x 256 threads, 1 block/CU -> all co-resident. Group = bid&7 owns 8
// batches; rank = bid>>3 owns 16 units. All shared state (h, flags) moves
// through the LLC (sc0 sc1) -> correct under ANY workgroup->XCD placement.
// Each wave polls independently and issues its h loads immediately on success.
__global__ __launch_bounds__(256, 1) void xlstm_rec(
    const ushortT* __restrict__ xb,    // [B*T][256] bf16 (clipped)
    const ushortT* __restrict__ UslT,  // [2112][512] bf16
    const ushortT* __restrict__ WslT,  // [2624][256] bf16
    const float* __restrict__ bi_p, const float* __restrict__ bf_p,
    const float* __restrict__ bo_p, const float* __restrict__ bc_p,
    const float* __restrict__ be_p,
    ushortT* __restrict__ Hbuf,        // [2][64][512] bf16
    unsigned* __restrict__ flags,      // [256]
    float* __restrict__ out)           // [64][512][512] fp32
{
    const int bid = blockIdx.x, tid = threadIdx.x;
    const int grp = bid & 7, rank = bid >> 3;
    const int wave = tid >> 6, lane = tid & 63;
    const int b0 = grp << 3;     // batch base
    const int u0 = rank << 4;    // unit base

    __shared__ float memF[8 * MEMF_PB];     // c ring: [pb][pu][slot(64)+pad] (thread-private rows)
    __shared__ float g_lds[4][8][16];       // i,f,o,ctilde
    __shared__ float e_lds[8][68];          // raw clipped e-logits (logical idx)
    __shared__ float w_lds[8][72];          // softmax numerators (physical slot)
    __shared__ float zm_lds[8][16];         // x_t @ Wm slice

    for (int i = tid; i < 8 * MEMF_PB; i += 256) memF[i] = 0.f;

    // ---- register-resident weight B-fragments ----
    int cols[2];
    float biasv[2];
#pragma unroll
    for (int nt = 0; nt < 2; ++nt) {
        int j = wave * 32 + nt * 16 + (lane & 15);
        if (j < 64) {
            int g = j >> 4, u = u0 + (j & 15);
            cols[nt] = g * 512 + u;
            biasv[nt] = (g == 0) ? bi_p[u] : (g == 1) ? bf_p[u] : (g == 2) ? bo_p[u] : bc_p[u];
        } else {
            cols[nt] = 2048 + (j - 64);
            biasv[nt] = be_p[j - 64];
        }
    }
    const int koct = (lane >> 4) * 8;
    bf16x8 B1[2][8], B2[2][16], B1m[8];
#pragma unroll
    for (int nt = 0; nt < 2; ++nt) {
        const ushortT* bw = WslT + cols[nt] * 256;
#pragma unroll
        for (int kt = 0; kt < 8; ++kt)
            B1[nt][kt] = *(const bf16x8*)(bw + kt * 32 + koct);
        const ushortT* bu = UslT + cols[nt] * 512;
#pragma unroll
        for (int kt = 0; kt < 16; ++kt)
            B2[nt][kt] = *(const bf16x8*)(bu + kt * 32 + koct);
    }
    if (wave == 1) {   // Wm fragment (zm = x@Wm via MFMA)
        const ushortT* bm = WslT + (2112 + u0 + (lane & 15)) * 256;
#pragma unroll
        for (int kt = 0; kt < 8; ++kt)
            B1m[kt] = *(const bf16x8*)(bm + kt * 32 + koct);
    }

    const int arow = lane & 7;
    const bool is_pw = (tid >= 64 && tid < 192);
    const int pb = (tid - 64) >> 4;
    const int pu = (tid - 64) & 15;
    const unsigned* fbase = flags + grp * 32 + (lane & 31);
    const bool mypoll = (lane < 32) && ((lane & 31) != rank);

    __syncthreads();

    bool sat = true;   // per-wave poll satisfaction (target = current t)

    for (int t = 0; t < T_SZ; ++t) {
        const int wp = t & 1, rp = wp ^ 1;

        // ---- phase A: prefetch x fragments; EACH wave polls for step t ----
        bf16x8 a1f[8];
        {
            const ushortT* xrow = xb + ((b0 + arow) * T_SZ + t) * D_SZ + koct;
#pragma unroll
            for (int kt = 0; kt < 8; ++kt)
                a1f[kt] = *(const bf16x8*)(xrow + kt * 32);
        }
        if (t > 0) {
            while (!__all(sat)) {
                unsigned v = 0;
                if (!sat) v = flag_ld(fbase);
                sat = sat || (v >= (unsigned)t);
            }
        }
        sat = !mypoll;   // reset for target t+1

        // ---- phase B: h loads (LLC) + MFMA + epilogue ----
        i32x4 hfrag[16];
        {
            const ushortT* hrow = Hbuf + (rp << 15) + (b0 + arow) * 512 + koct;
#pragma unroll
            for (int kt = 0; kt < 16; ++kt)
                asm volatile("global_load_dwordx4 %0, %1, off sc0 sc1"
                             : "=v"(hfrag[kt]) : "v"(hrow + kt * 32) : "memory");
        }
        f32x4 acc0 = {0.f, 0.f, 0.f, 0.f}, acc1 = {0.f, 0.f, 0.f, 0.f};
        f32x4 acc2 = {0.f, 0.f, 0.f, 0.f};
#pragma unroll
        for (int kt = 0; kt < 8; ++kt) {
            acc0 = __builtin_amdgcn_mfma_f32_16x16x32_bf16(a1f[kt], B1[0][kt], acc0, 0, 0, 0);
            acc1 = __builtin_amdgcn_mfma_f32_16x16x32_bf16(a1f[kt], B1[1][kt], acc1, 0, 0, 0);
        }
        if (wave == 1) {
#pragma unroll
            for (int kt = 0; kt < 8; ++kt)
                acc2 = __builtin_amdgcn_mfma_f32_16x16x32_bf16(a1f[kt], B1m[kt], acc2, 0, 0, 0);
        }
        asm volatile("s_waitcnt vmcnt(0)" ::: "memory");
        __builtin_amdgcn_sched_barrier(0);   // rule #18
#pragma unroll
        for (int kt = 0; kt < 16; ++kt) {
            bf16x8 a = __builtin_bit_cast(bf16x8, hfrag[kt]);
            acc0 = __builtin_amdgcn_mfma_f32_16x16x32_bf16(a, B2[0][kt], acc0, 0, 0, 0);
            acc1 = __builtin_amdgcn_mfma_f32_16x16x32_bf16(a, B2[1][kt], acc1, 0, 0, 0);
        }
        // epilogue: C/D layout col=lane&15, row=(lane>>4)*4+i (rows 0..7 in lanes<32)
        if (lane < 32) {
#pragma unroll
            for (int nt = 0; nt < 2; ++nt) {
                int j = wave * 32 + nt * 16 + (lane & 15);
                f32x4 a = nt ? acc1 : acc0;
#pragma unroll
                for (int i = 0; i < 4; ++i) {
                    int b = ((lane >> 4) << 2) + i;
                    float z = clip10(a[i] + biasv[nt]);
                    if (j < 64) {
                        int g = j >> 4;
                        g_lds[g][b][j & 15] = (g == 3) ? tanh_fast(z) : sigm_fast(z);
                    } else {
                        e_lds[b][j - 64] = z;
                    }
                }
            }
            if (wave == 1) {
#pragma unroll
                for (int i = 0; i < 4; ++i)
                    zm_lds[((lane >> 4) << 2) + i][lane & 15] = acc2[i];
            }
        }
        __syncthreads();   // (1) gates/e/zm ready

        // ---- phase C: pointwise with fused max-free softmax (waves 1,2) ----
        if (is_pw) {
            // numerators: physical slot p weight = exp(e[(t-1-p)&63]); |e|<=10 so
            // exp is fp32-safe without max subtraction (denom <= 64*e^10 ~ 1.4e6).
            const int base = pu * 4;
            const int k0 = t - 1 - base;
            float wv0 = __expf(e_lds[pb][(unsigned)(k0) & 63]);
            float wv1 = __expf(e_lds[pb][(unsigned)(k0 - 1) & 63]);
            float wv2 = __expf(e_lds[pb][(unsigned)(k0 - 2) & 63]);
            float wv3 = __expf(e_lds[pb][(unsigned)(k0 - 3) & 63]);
            float ssum = (wv0 + wv1) + (wv2 + wv3);
#pragma unroll
            for (int d = 1; d < 16; d <<= 1) ssum += __shfl_xor(ssum, d);
            float4 wq = {wv0, wv1, wv2, wv3};
            *(float4*)&w_lds[pb][base] = wq;
            asm volatile("" ::: "memory");   // keep ds_write before ds_reads (same-wave FIFO)
            // attn = sum_p w[p] * memF[pb][pu][p]  (vectorized)
            float attn = 0.f;
            const float4* wr = (const float4*)&w_lds[pb][0];
            const float4* mr = (const float4*)&memF[pb * MEMF_PB + pu * MEMF_ROW];
#pragma unroll
            for (int p4 = 0; p4 < 16; ++p4) {
                float4 w4 = wr[p4], m4 = mr[p4];
                attn = fmaf(w4.x, m4.x, attn);
                attn = fmaf(w4.y, m4.y, attn);
                attn = fmaf(w4.z, m4.z, attn);
                attn = fmaf(w4.w, m4.w, attn);
            }
            attn /= ssum;
            float ig = g_lds[0][pb][pu];
            float fg = g_lds[1][pb][pu];
            float og = g_lds[2][pb][pu];
            float ct = g_lds[3][pb][pu];
            float c = fg * (attn + zm_lds[pb][pu]) + ig * ct;
            float h = og * tanh_fast(c);
            memF[pb * MEMF_PB + pu * MEMF_ROW + (t & 63)] = c;   // read-before-write: holds c_{t-64}
            out[((b0 + pb) * T_SZ + t) * U_SZ + u0 + pu] = h;
            ushortT hv = f2b(h);
            const ushortT* haddr = Hbuf + (wp << 15) + (b0 + pb) * 512 + u0 + pu;
            asm volatile("global_store_short %0, %1, off sc0 sc1"
                         :: "v"(haddr), "v"((unsigned)hv) : "memory");
            asm volatile("s_waitcnt vmcnt(0)" ::: "memory");   // h ack'd at LLC
        }
        __syncthreads();   // (2) all h stores drained before release

        if (tid == 0) flag_st(flags + grp * 32 + rank, (unsigned)(t + 1));
    }
}

// ---------- launch ----------
extern "C" void kernel_launch(void* const* d_in, const int* in_sizes, int n_in,
                              void* d_out, int out_size, void* d_ws, size_t ws_size,
                              hipStream_t stream) {
    const float* x  = (const float*)d_in[0];
    const float* Wi = (const float*)d_in[1];
    const float* Ui = (const float*)d_in[2];
    const float* bi = (const float*)d_in[3];
    const float* Wf = (const float*)d_in[4];
    const float* Uf = (const float*)d_in[5];
    const float* bf = (const float*)d_in[6];
    const float* Wo = (const float*)d_in[7];
    const float* Uo = (const float*)d_in[8];
    const float* bo = (const float*)d_in[9];
    const float* Wc = (const float*)d_in[10];
    const float* Uc = (const float*)d_in[11];
    const float* bc = (const float*)d_in[12];
    const float* Wm = (const float*)d_in[13];
    const float* We = (const float*)d_in[14];
    const float* Ue = (const float*)d_in[15];
    const float* be = (const float*)d_in[16];

    char* ws = (char*)d_ws;
    const size_t off_xb    = 0;
    const size_t off_uslt  = off_xb + (size_t)B_SZ * T_SZ * D_SZ * 2;   // 16,777,216
    const size_t off_wslt  = off_uslt + (size_t)2112 * 512 * 2;         // +2,162,688
    const size_t off_hbuf  = off_wslt + (size_t)2624 * 256 * 2;         // +1,343,488
    const size_t off_flags = off_hbuf + (size_t)2 * 64 * 512 * 2;       // +131,072
    ushortT* xb      = (ushortT*)(ws + off_xb);
    ushortT* UslT    = (ushortT*)(ws + off_uslt);
    ushortT* WslT    = (ushortT*)(ws + off_wslt);
    ushortT* Hb      = (ushortT*)(ws + off_hbuf);
    unsigned* flags  = (unsigned*)(ws + off_flags);
    float* out = (float*)d_out;

    // zero H double-buffer + flags (contiguous; re-zeroed every replay)
    hipMemsetAsync(ws + off_hbuf, 0, 131072 + 1024, stream);

    prep_xb_k<<<2048, 256, 0, stream>>>(x, xb);
    prep_uw_k<<<2048, 256, 0, stream>>>(Ui, Uf, Uo, Uc, Ue, Wi, Wf, Wo, Wc, We, Wm,
                                        UslT, WslT);

    xlstm_rec<<<dim3(256), dim3(256), 0, stream>>>(
        xb, UslT, WslT, bi, bf, bo, bc, be, Hb, flags, out);
}